// Round 1
// baseline (486.592 us; speedup 1.0000x reference)
//
#include <hip/hip_runtime.h>
#include <stdint.h>

#define BATCH 8192

// ws byte offsets
#define OFF_W1R3    0            // uint32[96]   : w1 sign rows, 3 rows x 9 bits per word
#define OFF_W2B     1152         // uint32[1296] : w2 sign bits over ic (32) per (oc,k)
#define OFF_W3B     6336         // uint32[648]  : w3 sign bits over ic (16) per (oc,k)
#define OFF_WLB     8928         // uint64[20]   : wl sign bits, 128 bits per oc
#define OFF_SBL     9088         // float[10]    : sign(bl)
#define OFF_TTOT    9216         // int32[81]    : layer-1 window sums (global)
#define OFF_T2      9600         // int32[16]    : layer-2 thresholds
#define OFF_S3      9664         // int64[8]     : layer-3 channel sums
#define OFF_S2PART  9728         // int32[512*16]: per-block layer-2 partial sums
#define OFF_Z2      534528       // int16[8192*2304]
#define OFF_Z3      38283264     // int16[8192*128]
// total = 40380416 bytes (~40.4 MB)

// ---------------------------------------------------------------- K0: pack weights
__global__ __launch_bounds__(256) void k0_pack(const float* __restrict__ w1,
                                               const float* __restrict__ w2,
                                               const float* __restrict__ w3,
                                               const float* __restrict__ wl,
                                               const float* __restrict__ bl,
                                               uint8_t* __restrict__ ws) {
  uint32_t* W1R3 = (uint32_t*)(ws + OFF_W1R3);
  uint32_t* W2B  = (uint32_t*)(ws + OFF_W2B);
  uint32_t* W3B  = (uint32_t*)(ws + OFF_W3B);
  uint64_t* WLB  = (uint64_t*)(ws + OFF_WLB);
  float*    SBL  = (float*)(ws + OFF_SBL);
  int tid = threadIdx.x;
  // w1: (32,1,9,9). word i of oc holds rows 3i..3i+2 at bit offsets 0,9,18. bit=1 <=> w<0
  for (int e = tid; e < 96; e += 256) {
    int oc = e / 3, i = e % 3;
    uint32_t m = 0;
    for (int rr = 0; rr < 3; ++rr)
      for (int kw = 0; kw < 9; ++kw)
        if (w1[oc*81 + (3*i+rr)*9 + kw] < 0.f) m |= 1u << (rr*9 + kw);
    W1R3[e] = m;
  }
  // w2: (16,32,9,9) -> per (oc, k=kh*9+kw): 32 bits over ic
  for (int e = tid; e < 1296; e += 256) {
    int oc = e / 81, k = e % 81;
    uint32_t m = 0;
    for (int ic = 0; ic < 32; ++ic)
      if (w2[(oc*32 + ic)*81 + k] < 0.f) m |= 1u << ic;
    W2B[e] = m;
  }
  // w3: (8,16,9,9)
  for (int e = tid; e < 648; e += 256) {
    int oc = e / 81, k = e % 81;
    uint32_t m = 0;
    for (int ic = 0; ic < 16; ++ic)
      if (w3[(oc*16 + ic)*81 + k] < 0.f) m |= 1u << ic;
    W3B[e] = m;
  }
  // wl: (10,8,4,4) -> 128 bits per oc, bit j = ic*16 + (y*4+x)
  for (int e = tid; e < 20; e += 256) {
    int oc = e >> 1, word = e & 1;
    uint64_t m = 0;
    for (int b = 0; b < 64; ++b)
      if (wl[oc*128 + word*64 + b] < 0.f) m |= 1ull << b;
    WLB[e] = m;
  }
  if (tid < 10) SBL[tid] = (bl[tid] >= 0.f) ? 1.f : -1.f;
}

// ---------------------------------------------------------------- K1: layer-1 window sums
// T[kh*9+kw] += sum over 20x20 window at (kh,kw) of sign(x), per image, via integral image.
__global__ __launch_bounds__(256) void k1_tsum(const float* __restrict__ x,
                                               uint8_t* __restrict__ ws) {
  int* Ttot = (int*)(ws + OFF_TTOT);
  __shared__ uint16_t RP[4][28][29];  // per-wave row prefix (neg counts)
  __shared__ uint16_t P[4][29][29];   // per-wave 2D prefix
  __shared__ int Tacc[81];
  const int tid = threadIdx.x;
  const int wv = tid >> 6, ln = tid & 63;
  if (tid < 81) Tacc[tid] = 0;
  __syncthreads();
  for (int it = 0; it < 8; ++it) {
    int img = blockIdx.x * 32 + it * 4 + wv;
    const float* xi = x + (size_t)img * 784;
    if (ln < 28) {
      uint16_t cnt = 0;
      RP[wv][ln][0] = 0;
      for (int c = 0; c < 28; ++c) {
        cnt += (xi[ln*28 + c] < 0.f) ? 1 : 0;
        RP[wv][ln][c+1] = cnt;
      }
    }
    __syncthreads();
    if (ln < 29) {
      uint16_t run = 0;
      P[wv][0][ln] = 0;
      for (int i = 1; i <= 28; ++i) {
        run += RP[wv][i-1][ln];
        P[wv][i][ln] = run;
      }
    }
    __syncthreads();
    if (ln < 81) {
      int kh = ln / 9, kw = ln % 9;
      int cnt = (int)P[wv][kh+20][kw+20] - (int)P[wv][kh][kw+20]
              - (int)P[wv][kh+20][kw]  + (int)P[wv][kh][kw];
      atomicAdd(&Tacc[ln], 400 - 2*cnt);
    }
    __syncthreads();
  }
  if (tid < 81) atomicAdd(&Ttot[tid], Tacc[tid]);
}

// ---------------------------------------------------------------- K2: conv1 (recompute) + conv2
#define K2_IMGS 16
__global__ __launch_bounds__(256) void k2_conv12(const float* __restrict__ x,
                                                 uint8_t* __restrict__ ws) {
  const uint32_t* W1R3g = (const uint32_t*)(ws + OFF_W1R3);
  const uint32_t* W2Bg  = (const uint32_t*)(ws + OFF_W2B);
  const int* Ttot = (const int*)(ws + OFF_TTOT);
  int16_t* Z2 = (int16_t*)(ws + OFF_Z2);
  int* S2P = (int*)(ws + OFF_S2PART);

  __shared__ uint32_t rowm[K2_IMGS*28];   // binarized input rows (bit c = neg)
  __shared__ uint32_t w1r3[96];
  __shared__ uint32_t w2b[1296];
  __shared__ int tlds[81];
  __shared__ int t1s[32];
  __shared__ uint32_t A1[K2_IMGS*400];    // layer-1 activations, bit oc = neg
  __shared__ int s2acc[16];

  const int tid = threadIdx.x;
  const int img0 = blockIdx.x * K2_IMGS;

  for (int e = tid; e < 96; e += 256)   w1r3[e] = W1R3g[e];
  for (int e = tid; e < 1296; e += 256) w2b[e]  = W2Bg[e];
  if (tid < 81) tlds[tid] = Ttot[tid];
  if (tid < 16) s2acc[tid] = 0;
  for (int r = tid; r < K2_IMGS*28; r += 256) {
    int il = r / 28, rr = r % 28;
    const float4* xr = (const float4*)(x + (size_t)(img0 + il) * 784 + rr * 28);
    uint32_t m = 0;
    #pragma unroll
    for (int j = 0; j < 7; ++j) {
      float4 v = xr[j];
      if (v.x < 0.f) m |= 1u << (j*4+0);
      if (v.y < 0.f) m |= 1u << (j*4+1);
      if (v.z < 0.f) m |= 1u << (j*4+2);
      if (v.w < 0.f) m |= 1u << (j*4+3);
    }
    rowm[r] = m;
  }
  __syncthreads();

  // layer-1 thresholds (odd parity): t1 = smallest odd integer >= S1/N1
  if (tid < 32) {
    long long S = 0;
    for (int kh = 0; kh < 9; ++kh)
      for (int kw = 0; kw < 9; ++kw) {
        int bit = (w1r3[tid*3 + kh/3] >> ((kh%3)*9 + kw)) & 1;
        S += (long long)(1 - 2*bit) * tlds[kh*9 + kw];
      }
    const long long N1 = (long long)BATCH * 400;
    long long q = S / N1, rr = S % N1;
    long long t = q + (rr > 0 ? 1 : 0);
    if ((t & 1) == 0) t += 1;
    t1s[tid] = (int)t;
  }
  __syncthreads();

  // conv1 + binarize -> A1 (z1 = 81 - 2*mismatches; bit oc = (z1 < t1))
  for (int idx = tid; idx < K2_IMGS*400; idx += 256) {
    int il = idx / 400, p = idx % 400;
    int oh = p / 20, ow = p % 20;
    uint32_t win3[3];
    #pragma unroll
    for (int i = 0; i < 3; ++i) {
      uint32_t b0 = (rowm[il*28 + oh + 3*i    ] >> ow) & 0x1FFu;
      uint32_t b1 = (rowm[il*28 + oh + 3*i + 1] >> ow) & 0x1FFu;
      uint32_t b2 = (rowm[il*28 + oh + 3*i + 2] >> ow) & 0x1FFu;
      win3[i] = b0 | (b1 << 9) | (b2 << 18);
    }
    uint32_t mask = 0;
    #pragma unroll
    for (int oc = 0; oc < 32; ++oc) {
      int mm = __popc(win3[0] ^ w1r3[oc*3])
             + __popc(win3[1] ^ w1r3[oc*3+1])
             + __popc(win3[2] ^ w1r3[oc*3+2]);
      int z1 = 81 - 2*mm;
      mask |= (uint32_t)(z1 < t1s[oc]) << oc;
    }
    A1[il*400 + p] = mask;
  }
  __syncthreads();

  // conv2: thread = (image, 3-pixel row chunk), all 16 oc. 768 groups / block.
  for (int r = 0; r < 3; ++r) {
    int G = tid + r*256;
    int il = G / 48, tri = G % 48;
    int oy = tri >> 2, ox = (tri & 3) * 3;
    const uint32_t* A = &A1[il*400];
    for (int ocq = 0; ocq < 4; ++ocq) {
      int acc[4][3];
      #pragma unroll
      for (int a_ = 0; a_ < 4; ++a_)
        #pragma unroll
        for (int b_ = 0; b_ < 3; ++b_) acc[a_][b_] = 0;
      #pragma unroll
      for (int kh = 0; kh < 9; ++kh) {
        uint32_t a[11];
        #pragma unroll
        for (int j = 0; j < 11; ++j) a[j] = A[(oy+kh)*20 + ox + j];
        #pragma unroll
        for (int o4 = 0; o4 < 4; ++o4) {
          int oc = ocq*4 + o4;
          #pragma unroll
          for (int kw = 0; kw < 9; ++kw) {
            uint32_t w = w2b[oc*81 + kh*9 + kw];
            acc[o4][0] += __popc(a[kw]   ^ w);
            acc[o4][1] += __popc(a[kw+1] ^ w);
            acc[o4][2] += __popc(a[kw+2] ^ w);
          }
        }
      }
      #pragma unroll
      for (int o4 = 0; o4 < 4; ++o4) {
        int oc = ocq*4 + o4;
        int s_local = 0;
        #pragma unroll
        for (int px = 0; px < 3; ++px) {
          int z2v = 2592 - 2*acc[o4][px];
          s_local += z2v;
          Z2[(size_t)(img0+il)*2304 + oc*144 + oy*12 + ox + px] = (int16_t)z2v;
        }
        atomicAdd(&s2acc[oc], s_local);
      }
    }
  }
  __syncthreads();
  if (tid < 16) S2P[blockIdx.x*16 + tid] = s2acc[tid];
}

// ---------------------------------------------------------------- K2b: reduce S2 partials -> t2
__global__ __launch_bounds__(256) void k2b_reduce(uint8_t* __restrict__ ws) {
  const int* S2P = (const int*)(ws + OFF_S2PART);
  int* T2 = (int*)(ws + OFF_T2);
  __shared__ long long part[256];
  int tid = threadIdx.x;
  int c = tid & 15, g = tid >> 4;  // 16 groups over 512 blocks
  long long s = 0;
  for (int b = g*32; b < g*32 + 32; ++b) s += S2P[b*16 + c];
  part[tid] = s;
  __syncthreads();
  if (tid < 16) {
    long long S = 0;
    for (int g2 = 0; g2 < 16; ++g2) S += part[g2*16 + tid];
    const long long N2 = (long long)BATCH * 144;
    long long q = S / N2, r = S % N2;
    long long t = q + (r > 0 ? 1 : 0);
    if (t & 1) t += 1;   // z2 is even
    T2[tid] = (int)t;
  }
}

// ---------------------------------------------------------------- K3: conv3
__global__ __launch_bounds__(256) void k3_conv3(uint8_t* __restrict__ ws) {
  const int16_t* Z2 = (const int16_t*)(ws + OFF_Z2);
  const int* T2 = (const int*)(ws + OFF_T2);
  const uint32_t* W3Bg = (const uint32_t*)(ws + OFF_W3B);
  int16_t* Z3 = (int16_t*)(ws + OFF_Z3);
  unsigned long long* S3 = (unsigned long long*)(ws + OFF_S3);

  __shared__ uint32_t w3b[648];
  __shared__ int t2[16];
  __shared__ uint32_t A2[2][144];
  __shared__ int s3acc[8];

  const int tid = threadIdx.x;
  for (int e = tid; e < 648; e += 256) w3b[e] = W3Bg[e];
  if (tid < 16) t2[tid] = T2[tid];
  if (tid < 8) s3acc[tid] = 0;
  __syncthreads();

  const int half = tid >> 7, h = tid & 127;
  for (int it = 0; it < 8; ++it) {
    int img = blockIdx.x * 16 + it*2 + half;
    const int16_t* z2i = Z2 + (size_t)img * 2304;
    for (int p = h; p < 144; p += 128) {
      uint32_t m = 0;
      #pragma unroll
      for (int ic = 0; ic < 16; ++ic)
        if ((int)z2i[ic*144 + p] < t2[ic]) m |= 1u << ic;
      A2[half][p] = m;
    }
    __syncthreads();
    {
      int oc = h >> 4, pix = h & 15;
      int oy = pix >> 2, ox = pix & 3;
      int mism = 0;
      for (int kh = 0; kh < 9; ++kh)
        #pragma unroll
        for (int kw = 0; kw < 9; ++kw)
          mism += __popc(A2[half][(oy+kh)*12 + ox + kw] ^ w3b[oc*81 + kh*9 + kw]);
      int z3 = 1296 - 2*mism;
      Z3[(size_t)img*128 + h] = (int16_t)z3;
      atomicAdd(&s3acc[oc], z3);
    }
    __syncthreads();
  }
  if (tid < 8)
    atomicAdd(&S3[tid], (unsigned long long)(long long)s3acc[tid]);
}

// ---------------------------------------------------------------- K4: conv4 + bias -> out
__global__ __launch_bounds__(256) void k4_final(uint8_t* __restrict__ ws,
                                                float* __restrict__ out) {
  const int16_t* Z3 = (const int16_t*)(ws + OFF_Z3);
  const long long* S3 = (const long long*)(ws + OFF_S3);
  const uint64_t* WLBg = (const uint64_t*)(ws + OFF_WLB);
  const float* SBLg = (const float*)(ws + OFF_SBL);
  __shared__ int t3[8];
  __shared__ uint64_t wlb[20];
  __shared__ float sbl[10];
  const int tid = threadIdx.x;
  if (tid < 8) {
    long long S = S3[tid];
    const long long N3 = (long long)BATCH * 16;
    long long q = S / N3, r = S % N3;
    long long t = q + (r > 0 ? 1 : 0);
    if (t & 1) t += 1;   // z3 is even
    t3[tid] = (int)t;
  }
  if (tid < 20) wlb[tid] = WLBg[tid];
  if (tid < 10) sbl[tid] = SBLg[tid];
  __syncthreads();
  int img = blockIdx.x * 256 + tid;
  const int16_t* z3i = Z3 + (size_t)img * 128;
  uint64_t a0 = 0, a1 = 0;
  for (int j = 0; j < 64; ++j)
    if ((int)z3i[j] < t3[j >> 4]) a0 |= 1ull << j;
  for (int j = 0; j < 64; ++j)
    if ((int)z3i[64 + j] < t3[(64 + j) >> 4]) a1 |= 1ull << j;
  #pragma unroll
  for (int oc = 0; oc < 10; ++oc) {
    int mism = __popcll(a0 ^ wlb[oc*2]) + __popcll(a1 ^ wlb[oc*2 + 1]);
    out[(size_t)img*10 + oc] = (float)(128 - 2*mism) + sbl[oc];
  }
}

// ----------------------------------------------------------------
extern "C" void kernel_launch(void* const* d_in, const int* in_sizes, int n_in,
                              void* d_out, int out_size, void* d_ws, size_t ws_size,
                              hipStream_t stream) {
  (void)in_sizes; (void)n_in; (void)out_size; (void)ws_size;
  const float* x  = (const float*)d_in[0];
  const float* w1 = (const float*)d_in[1];
  // d_in[2] = b1, d_in[4] = b2, d_in[6] = b3: biases cancel under BN -> unused
  const float* w2 = (const float*)d_in[3];
  const float* w3 = (const float*)d_in[5];
  const float* wl = (const float*)d_in[7];
  const float* bl = (const float*)d_in[8];
  uint8_t* ws = (uint8_t*)d_ws;
  float* out = (float*)d_out;

  // zero T_total / T2 / S3 accumulator region (ws is poisoned 0xAA each call)
  hipMemsetAsync(ws + OFF_TTOT, 0, 512, stream);
  k0_pack<<<1, 256, 0, stream>>>(w1, w2, w3, wl, bl, ws);
  k1_tsum<<<256, 256, 0, stream>>>(x, ws);
  k2_conv12<<<512, 256, 0, stream>>>(x, ws);
  k2b_reduce<<<1, 256, 0, stream>>>(ws);
  k3_conv3<<<512, 256, 0, stream>>>(ws);
  k4_final<<<32, 256, 0, stream>>>(ws, out);
}